// Round 4
// baseline (425.418 us; speedup 1.0000x reference)
//
#include <hip/hip_runtime.h>
#include <math.h>

#define NPTS 4096
#define BLK 256
#define V 16
#define NPROJ 256
#define NBATCH 32

// LDS placement: element idx lives at float address
//   phi(idx) = idx ^ (((idx>>8)&3)<<2) ^ (((idx>>9)&1)<<4)
// phi is GF(2)-linear: phi(i^m) = phi(i)^phi(m), so a reversal partner
// (idx ^ MASK) sits at own_addr ^ phi(MASK) with phi(MASK) compile-time.
// Normalized bitonic network: every merge starts with a reversal pairing
// i <-> i^(2s-1) (fused into LDS reads / shuffles), after which ALL
// compare-exchanges are ascending min/max — zero direction logic.

__device__ __forceinline__ void cmpex_asc(float& a, float& b) {
    const float lo = fminf(a, b), hi = fmaxf(a, b);
    a = lo; b = hi;
}

// Ascending cleaner stages j = JB, JB/2, ..., 1 over the 16 registers.
template<int JB>
__device__ __forceinline__ void stages_asc(float* v) {
#pragma unroll
    for (int r = 0; r < V; ++r)
        if ((r & JB) == 0) cmpex_asc(v[r], v[r | JB]);
    if constexpr (JB > 1) stages_asc<(JB >> 1)>(v);
}

// In-register reversal step for merge size MASK+1 (MASK <= 15).
template<int MASK>
__device__ __forceinline__ void rev_inreg(float* v) {
    constexpr int S = (MASK + 1) >> 1;
#pragma unroll
    for (int r = 0; r < V; ++r) {
        if ((r & S) == 0) {
            float a = v[r], b = v[r ^ MASK];
            v[r] = fminf(a, b);
            v[r ^ MASK] = fmaxf(a, b);
        }
    }
}

// Merge-32 reversal: partner lane t^1, registers reversed. Per-lane keep
// (lower half -> min, upper -> max), uniform per thread.
__device__ __forceinline__ void rev32_shfl(float* v, bool odd) {
#pragma unroll
    for (int r = 0; r < 8; ++r) {
        const float pa = __shfl_xor(v[r ^ 15], 1, 64);
        const float pb = __shfl_xor(v[r], 1, 64);
        v[r]      = odd ? fmaxf(v[r], pa)      : fminf(v[r], pa);
        v[r ^ 15] = odd ? fmaxf(v[r ^ 15], pb) : fminf(v[r ^ 15], pb);
    }
}

// L layout: thread owns idx = (t<<4)|r. float4 base (t^t5b)<<2, quad q^t54.
__device__ __forceinline__ void writeL(float* s, const float* v, int fb4, int t54) {
    float4* p4 = (float4*)s + fb4;
#pragma unroll
    for (int q = 0; q < 4; ++q)
        p4[q ^ t54] = make_float4(v[4 * q], v[4 * q + 1], v[4 * q + 2], v[4 * q + 3]);
}
__device__ __forceinline__ void readL(const float* s, float* v, int fb4, int t54) {
    const float4* p4 = (const float4*)s + fb4;
#pragma unroll
    for (int q = 0; q < 4; ++q) {
        float4 f = p4[q ^ t54];
        v[4 * q] = f.x; v[4 * q + 1] = f.y; v[4 * q + 2] = f.z; v[4 * q + 3] = f.w;
    }
}
// M layout: thread owns idx = (t74<<8)|(r<<4)|t30. Bases bE (even r) / bO (odd r).
__device__ __forceinline__ void writeM(float* se, float* so, const float* v) {
#pragma unroll
    for (int r = 0; r < V; ++r) {
        if (r & 1) so[r * 16] = v[r]; else se[r * 16] = v[r];
    }
}
__device__ __forceinline__ void readM(const float* se, const float* so, float* v) {
#pragma unroll
    for (int r = 0; r < V; ++r) {
        v[r] = (r & 1) ? so[r * 16] : se[r * 16];
    }
}
// M read fused with reversal for merge 2s (PC = phi(2s-1), SRB = reg bit of s).
template<int PC, int SRB>
__device__ __forceinline__ void readM_rev(const float* s, int bE, int bO, float* v) {
#pragma unroll
    for (int r = 0; r < V; ++r) {
        const int own = ((r & 1) ? bO : bE) + r * 16;
        const float a = s[own], b = s[own ^ PC];
        v[r] = (r & SRB) ? fmaxf(a, b) : fminf(a, b);
    }
}
// H layout: thread owns idx = (r<<8)|t. Four bases by r&3.
__device__ __forceinline__ void writeH(float* s, const float* v,
                                       int b0, int b1, int b2, int b3) {
#pragma unroll
    for (int r = 0; r < V; ++r) {
        const int bh = ((r & 3) == 0) ? b0 : ((r & 3) == 1) ? b1 : ((r & 3) == 2) ? b2 : b3;
        s[(r << 8) + bh] = v[r];
    }
}
// H read fused with reversal.
template<int PC, int SRB>
__device__ __forceinline__ void readH_rev(const float* s, float* v,
                                          int b0, int b1, int b2, int b3) {
#pragma unroll
    for (int r = 0; r < V; ++r) {
        const int bh = ((r & 3) == 0) ? b0 : ((r & 3) == 1) ? b1 : ((r & 3) == 2) ? b2 : b3;
        const int own = (r << 8) + bh;
        const float a = s[own], b = s[own ^ PC];
        v[r] = (r & SRB) ? fmaxf(a, b) : fminf(a, b);
    }
}

__global__ __launch_bounds__(BLK) void swd_kernel(
    const float* __restrict__ x, const float* __restrict__ y,
    const float* __restrict__ theta, const float* __restrict__ rot,
    float* __restrict__ per_batch) {
    __shared__ float xs[NPTS];
    __shared__ float ys[NPTS];

    const int t = threadIdx.x;
    const int p = blockIdx.x;
    const int b = blockIdx.y;

    // proj[e] = sum_d theta[p,d] * rot[b,d,e]
    const float t0 = theta[p * 3 + 0], t1 = theta[p * 3 + 1], t2 = theta[p * 3 + 2];
    const float* R = rot + b * 9;
    const float p0 = t0 * R[0] + t1 * R[3] + t2 * R[6];
    const float p1 = t0 * R[1] + t1 * R[4] + t2 * R[7];
    const float p2 = t0 * R[2] + t1 * R[5] + t2 * R[8];

    // Load 16 points of each array (L layout: global idx = t*16+r), project.
    float vx[V], vy[V];
    {
        const float4* xb4 = (const float4*)(x + (size_t)b * NPTS * 3 + (size_t)t * V * 3);
        const float4* yb4 = (const float4*)(y + (size_t)b * NPTS * 3 + (size_t)t * V * 3);
#pragma unroll
        for (int g = 0; g < 4; ++g) {
            float4 a = xb4[g * 3 + 0], c = xb4[g * 3 + 1], d = xb4[g * 3 + 2];
            vx[4 * g + 0] = a.x * p0 + a.y * p1 + a.z * p2;
            vx[4 * g + 1] = a.w * p0 + c.x * p1 + c.y * p2;
            vx[4 * g + 2] = c.z * p0 + c.w * p1 + d.x * p2;
            vx[4 * g + 3] = d.y * p0 + d.z * p1 + d.w * p2;
            a = yb4[g * 3 + 0]; c = yb4[g * 3 + 1]; d = yb4[g * 3 + 2];
            vy[4 * g + 0] = a.x * p0 + a.y * p1 + a.z * p2;
            vy[4 * g + 1] = a.w * p0 + c.x * p1 + c.y * p2;
            vy[4 * g + 2] = c.z * p0 + c.w * p1 + d.x * p2;
            vy[4 * g + 3] = d.y * p0 + d.z * p1 + d.w * p2;
        }
    }

    // Precomputed phi addressing.
    const int t5b = (t >> 5) & 1;
    const int t54 = (t >> 4) & 3;
    const int fb4 = (t ^ t5b) << 2;                    // L float4 base
    const int t74 = t >> 4, t30 = t & 15;
    const int baseM = (t74 << 8) | (t30 ^ (t54 << 2)); // M float base
    const int bME = baseM + (t5b << 4);
    const int bMO = baseM - (t5b << 4);
    const int bH0 = t;                                 // H bases, by r&3
    const int bH1 = t ^ 4;
    const int bH2 = t ^ 8 ^ 16;
    const int bH3 = t ^ 12 ^ 16;

#define WRL writeL(xs, vx, fb4, t54); writeL(ys, vy, fb4, t54);
#define RDL readL(xs, vx, fb4, t54); readL(ys, vy, fb4, t54);
#define WRM writeM(xs + bME, xs + bMO, vx); writeM(ys + bME, ys + bMO, vy);
#define RDM readM(xs + bME, xs + bMO, vx); readM(ys + bME, ys + bMO, vy);
#define WRH writeH(xs, vx, bH0, bH1, bH2, bH3); writeH(ys, vy, bH0, bH1, bH2, bH3);
#define SYNC __syncthreads();

    // ---- in-register sort of 16 (merges 2..16), all ascending ----
    rev_inreg<1>(vx);  rev_inreg<1>(vy);
    rev_inreg<3>(vx);  rev_inreg<3>(vy);  stages_asc<1>(vx); stages_asc<1>(vy);
    rev_inreg<7>(vx);  rev_inreg<7>(vy);  stages_asc<2>(vx); stages_asc<2>(vy);
    rev_inreg<15>(vx); rev_inreg<15>(vy); stages_asc<4>(vx); stages_asc<4>(vy);

    // ---- merge 32: shuffle reversal + in-register cleaner ----
    const bool odd = (t & 1) != 0;
    rev32_shfl(vx, odd); rev32_shfl(vy, odd);
    stages_asc<8>(vx); stages_asc<8>(vy);

    // ---- merge 64: rev in M (PC=phi(63)=63, s-bit 5 -> reg bit 1) ----
    WRL SYNC
    readM_rev<63, 2>(xs, bME, bMO, vx); readM_rev<63, 2>(ys, bME, bMO, vy); SYNC
    stages_asc<1>(vx); stages_asc<1>(vy);          // j=16
    WRM SYNC RDL SYNC
    stages_asc<8>(vx); stages_asc<8>(vy);          // j=8..1

    // ---- merge 128 (PC=127, s-bit 6 -> reg bit 2) ----
    WRL SYNC
    readM_rev<127, 4>(xs, bME, bMO, vx); readM_rev<127, 4>(ys, bME, bMO, vy); SYNC
    stages_asc<2>(vx); stages_asc<2>(vy);          // j=32,16
    WRM SYNC RDL SYNC
    stages_asc<8>(vx); stages_asc<8>(vy);

    // ---- merge 256 (PC=255, s-bit 7 -> reg bit 3) ----
    WRL SYNC
    readM_rev<255, 8>(xs, bME, bMO, vx); readM_rev<255, 8>(ys, bME, bMO, vy); SYNC
    stages_asc<4>(vx); stages_asc<4>(vy);          // j=64,32,16
    WRM SYNC RDL SYNC
    stages_asc<8>(vx); stages_asc<8>(vy);

    // ---- merge 512: rev in H (PC=phi(511)=507, s-bit 8 -> reg bit 0) ----
    WRL SYNC
    readH_rev<507, 1>(xs, vx, bH0, bH1, bH2, bH3);
    readH_rev<507, 1>(ys, vy, bH0, bH1, bH2, bH3); SYNC
    WRH SYNC RDM SYNC
    stages_asc<8>(vx); stages_asc<8>(vy);          // j=128..16
    WRM SYNC RDL SYNC
    stages_asc<8>(vx); stages_asc<8>(vy);          // j=8..1

    // ---- merge 1024 (PC=phi(1023)=995, s-bit 9 -> reg bit 1) ----
    WRL SYNC
    readH_rev<995, 2>(xs, vx, bH0, bH1, bH2, bH3);
    readH_rev<995, 2>(ys, vy, bH0, bH1, bH2, bH3); SYNC
    stages_asc<1>(vx); stages_asc<1>(vy);          // j=256
    WRH SYNC RDM SYNC
    stages_asc<8>(vx); stages_asc<8>(vy);
    WRM SYNC RDL SYNC
    stages_asc<8>(vx); stages_asc<8>(vy);

    // ---- merge 2048 (PC=phi(2047)=2019, s-bit 10 -> reg bit 2) ----
    WRL SYNC
    readH_rev<2019, 4>(xs, vx, bH0, bH1, bH2, bH3);
    readH_rev<2019, 4>(ys, vy, bH0, bH1, bH2, bH3); SYNC
    stages_asc<2>(vx); stages_asc<2>(vy);          // j=512,256
    WRH SYNC RDM SYNC
    stages_asc<8>(vx); stages_asc<8>(vy);
    WRM SYNC RDL SYNC
    stages_asc<8>(vx); stages_asc<8>(vy);

    // ---- merge 4096 (PC=phi(4095)=4067, s-bit 11 -> reg bit 3) ----
    WRL SYNC
    readH_rev<4067, 8>(xs, vx, bH0, bH1, bH2, bH3);
    readH_rev<4067, 8>(ys, vy, bH0, bH1, bH2, bH3); SYNC
    stages_asc<4>(vx); stages_asc<4>(vy);          // j=1024,512,256
    WRH SYNC RDM SYNC
    stages_asc<8>(vx); stages_asc<8>(vy);
    WRM SYNC RDL SYNC
    stages_asc<8>(vx); stages_asc<8>(vy);

    // Sorted ascending (L layout). Sum squared differences.
    float s = 0.0f;
#pragma unroll
    for (int r = 0; r < V; ++r) {
        const float d = vx[r] - vy[r];
        s += d * d;
    }

    // Wave reduce, cross-wave via (now-free) xs, one atomic per block.
    for (int off = 32; off > 0; off >>= 1) s += __shfl_down(s, off, 64);
    const int lane = t & 63;
    const int wave = t >> 6;
    if (lane == 0) xs[wave] = s;
    __syncthreads();
    if (t == 0) {
        float tot = xs[0] + xs[1] + xs[2] + xs[3];
        atomicAdd(&per_batch[b], tot);
    }
}

__global__ void finalize_kernel(const float* __restrict__ per_batch, float* __restrict__ out) {
    const int t = threadIdx.x;  // 64 threads
    float v = (t < NBATCH) ? sqrtf(per_batch[t] * (1.0f / (float)NPROJ)) : 0.0f;
    for (int off = 32; off > 0; off >>= 1) v += __shfl_down(v, off, 64);
    if (t == 0) out[0] = v * (1.0f / (float)NBATCH);
}

extern "C" void kernel_launch(void* const* d_in, const int* in_sizes, int n_in,
                              void* d_out, int out_size, void* d_ws, size_t ws_size,
                              hipStream_t stream) {
    const float* x = (const float*)d_in[0];
    const float* y = (const float*)d_in[1];
    const float* theta = (const float*)d_in[2];
    const float* rot = (const float*)d_in[3];
    float* per_batch = (float*)d_ws;
    float* out = (float*)d_out;

    hipMemsetAsync(per_batch, 0, NBATCH * sizeof(float), stream);

    dim3 grid(NPROJ, NBATCH);
    swd_kernel<<<grid, BLK, 0, stream>>>(x, y, theta, rot, per_batch);

    finalize_kernel<<<1, 64, 0, stream>>>(per_batch, out);
}